// Round 1
// baseline (181.150 us; speedup 1.0000x reference)
//
#include <hip/hip_runtime.h>
#include <hip/hip_bf16.h>

// Problem constants (B=4, S=4096, A=2, H=8, DH=128, DM=2048)
#define T_TOK 16384
#define NH 8
#define DHD 128
#define DMD 2048
#define NBUCKET 64

typedef __attribute__((ext_vector_type(8))) short bf16x8;
typedef __attribute__((ext_vector_type(4))) float f32x4;

__device__ inline short f2b(float x) {
    __hip_bfloat16 h = __float2bfloat16(x);
    return *reinterpret_cast<short*>(&h);
}

// ---------------- ws layout (bytes) ----------------
// 0      : hist[64]       (zeroed each call)
// 256    : offsets[64]
// 512    : cursor[64]     (zeroed each call)
// 768    : ntiles (int)
// 1024   : tiles[256][4] ints (4 KB)
// 8192   : keys[16384]    (64 KB)
// 73728  : perm[16384]    (64 KB)
// 262144 : Wt bf16 [8][2048][128] (4 MB)

__global__ void k_keys(const int* __restrict__ idx, int* __restrict__ keys,
                       int* __restrict__ hist) {
    int t = blockIdx.x * 256 + threadIdx.x;
    if (t < T_TOK) {
        int h0 = idx[2 * t], h1 = idx[2 * t + 1];
        int key = h0 * NH + h1;
        keys[t] = key;
        atomicAdd(&hist[key], 1);
    }
}

__global__ void k_scan(const int* __restrict__ hist, int* __restrict__ offs,
                       int* __restrict__ tiles, int* __restrict__ ntiles) {
    if (threadIdx.x == 0) {
        int acc = 0, nt = 0;
        for (int k = 0; k < NBUCKET; ++k) {
            offs[k] = acc;
            int n = hist[k];
            for (int s = 0; s < n; s += 128) {
                tiles[4 * nt + 0] = k;
                tiles[4 * nt + 1] = acc + s;
                tiles[4 * nt + 2] = (n - s) < 128 ? (n - s) : 128;
                tiles[4 * nt + 3] = 0;
                ++nt;
            }
            acc += n;
        }
        *ntiles = nt;
    }
}

__global__ void k_scatter(const int* __restrict__ keys, const int* __restrict__ offs,
                          int* __restrict__ cursor, int* __restrict__ perm) {
    int t = blockIdx.x * 256 + threadIdx.x;
    if (t < T_TOK) {
        int key = keys[t];
        int pos = offs[key] + atomicAdd(&cursor[key], 1);
        perm[pos] = t;
    }
}

// W [h][d][m] f32  ->  Wt [h][m][d] bf16
__global__ void k_wt(const float* __restrict__ W, __hip_bfloat16* __restrict__ Wt) {
    int h = blockIdx.y;
    int m = blockIdx.x * 256 + threadIdx.x;
    for (int d0 = 0; d0 < DHD; d0 += 8) {
        bf16x8 o;
#pragma unroll
        for (int j = 0; j < 8; ++j) {
            float v = W[((size_t)h * DHD + d0 + j) * DMD + m];
            o[j] = f2b(v);
        }
        *(bf16x8*)(Wt + ((size_t)h * DMD + m) * DHD + d0) = o;
    }
}

// GEMM per head-pair bucket: A [rows<=128, K=256] = [p0*x0 | p1*x1] (bf16)
//                            B [256, 128] = [W[h0]; W[h1]] cols ncol..ncol+127
__global__ __launch_bounds__(256) void k_gemm(
    const float* __restrict__ emb, const float* __restrict__ probs,
    const __hip_bfloat16* __restrict__ Wt, const float* __restrict__ bias,
    const int* __restrict__ perm, const int* __restrict__ tiles,
    const int* __restrict__ ntiles, float* __restrict__ out) {
    int tile_id = blockIdx.y;
    if (tile_id >= *ntiles) return;
    int key   = tiles[4 * tile_id + 0];
    int row0  = tiles[4 * tile_id + 1];
    int nrows = tiles[4 * tile_id + 2];
    int h0 = key >> 3, h1 = key & 7;
    int ncol = blockIdx.x * 128;

    __shared__ __hip_bfloat16 As[128][72];  // row stride 144 B (16B-aligned)
    __shared__ __hip_bfloat16 Bs[128][72];  // Bs[n][k]
    __shared__ int   s_tok[128];
    __shared__ float s_p0[128], s_p1[128];

    int tid = threadIdx.x;
    if (tid < 128) {
        int i = tid;
        int t = -1; float p0 = 0.f, p1 = 0.f;
        if (i < nrows) {
            t = perm[row0 + i];
            p0 = probs[2 * t];
            p1 = probs[2 * t + 1];
        }
        s_tok[i] = t; s_p0[i] = p0; s_p1[i] = p1;
    }
    __syncthreads();

    f32x4 acc[4][4];
#pragma unroll
    for (int i = 0; i < 4; ++i)
#pragma unroll
        for (int j = 0; j < 4; ++j) acc[i][j] = (f32x4){0.f, 0.f, 0.f, 0.f};

    int lane = tid & 63, wave = tid >> 6;
    int wm = (wave >> 1) * 64, wn = (wave & 1) * 64;
    int l15 = lane & 15, lq = lane >> 4;

    int srow  = tid >> 1;        // staging row (0..127)
    int shalf = tid & 1;         // staging half
    int d0    = shalf * 32;

    for (int ks = 0; ks < 4; ++ks) {
        int kg0   = ks * 64;
        int a     = kg0 >> 7;    // which of the 2 attention slots
        int dbase = kg0 & 127;   // 0 or 64 within DH

        // ---- stage A: rows = gathered tokens, scaled by p, cast bf16
        {
            int i = srow;
            int t = s_tok[i];
            int ts = t < 0 ? 0 : t;
            float p = a ? s_p1[i] : s_p0[i];  // p==0 for padded rows -> zero row
            const float* src = emb + ((size_t)(2 * ts + a)) * DHD + dbase + d0;
#pragma unroll
            for (int j = 0; j < 4; ++j) {
                f32x4 f0 = ((const f32x4*)src)[2 * j];
                f32x4 f1 = ((const f32x4*)src)[2 * j + 1];
                bf16x8 o;
                o[0] = f2b(p * f0.x); o[1] = f2b(p * f0.y);
                o[2] = f2b(p * f0.z); o[3] = f2b(p * f0.w);
                o[4] = f2b(p * f1.x); o[5] = f2b(p * f1.y);
                o[6] = f2b(p * f1.z); o[7] = f2b(p * f1.w);
                *(bf16x8*)&As[i][d0 + 8 * j] = o;
            }
        }
        // ---- stage B: Bs[n][k] = Wt[h][ncol+n][dbase+k], direct bf16 copy
        {
            int n = srow;
            int h = (kg0 < DHD) ? h0 : h1;
            const bf16x8* src =
                (const bf16x8*)(Wt + ((size_t)(h * DMD + ncol + n)) * DHD + dbase + d0);
#pragma unroll
            for (int j = 0; j < 4; ++j) {
                ((bf16x8*)&Bs[n][d0])[j] = src[j];
            }
        }
        __syncthreads();

#pragma unroll
        for (int ki = 0; ki < 2; ++ki) {
            bf16x8 af[4], bfr[4];
#pragma unroll
            for (int mi = 0; mi < 4; ++mi)
                af[mi] = *(const bf16x8*)&As[wm + mi * 16 + l15][ki * 32 + lq * 8];
#pragma unroll
            for (int ni = 0; ni < 4; ++ni)
                bfr[ni] = *(const bf16x8*)&Bs[wn + ni * 16 + l15][ki * 32 + lq * 8];
#pragma unroll
            for (int mi = 0; mi < 4; ++mi)
#pragma unroll
                for (int ni = 0; ni < 4; ++ni)
                    acc[mi][ni] = __builtin_amdgcn_mfma_f32_16x16x32_bf16(
                        af[mi], bfr[ni], acc[mi][ni], 0, 0, 0);
        }
        __syncthreads();
    }

    // ---- epilogue: add prob-weighted bias, scatter rows to out
#pragma unroll
    for (int ni = 0; ni < 4; ++ni) {
        int c = ncol + wn + ni * 16 + l15;
        float b0 = bias[h0 * DMD + c];
        float b1 = bias[h1 * DMD + c];
#pragma unroll
        for (int mi = 0; mi < 4; ++mi) {
#pragma unroll
            for (int r = 0; r < 4; ++r) {
                int i = wm + mi * 16 + lq * 4 + r;
                int t = s_tok[i];
                if (t >= 0) {
                    out[(size_t)t * DMD + c] =
                        acc[mi][ni][r] + s_p0[i] * b0 + s_p1[i] * b1;
                }
            }
        }
    }
}

extern "C" void kernel_launch(void* const* d_in, const int* in_sizes, int n_in,
                              void* d_out, int out_size, void* d_ws, size_t ws_size,
                              hipStream_t stream) {
    const float* emb      = (const float*)d_in[0];  // (B,S,A,DH) f32
    const int*   sel_idx  = (const int*)d_in[1];    // (B,S,A) i32
    const float* sel_prob = (const float*)d_in[2];  // (B,S,A) f32
    const float* W        = (const float*)d_in[3];  // (H,DH,DM) f32
    const float* bias     = (const float*)d_in[4];  // (H,DM) f32
    float* out = (float*)d_out;

    char* ws = (char*)d_ws;
    int* hist   = (int*)(ws + 0);
    int* offs   = (int*)(ws + 256);
    int* cursor = (int*)(ws + 512);
    int* ntiles = (int*)(ws + 768);
    int* tiles  = (int*)(ws + 1024);
    int* keys   = (int*)(ws + 8192);
    int* perm   = (int*)(ws + 8192 + 65536);
    __hip_bfloat16* Wt = (__hip_bfloat16*)(ws + 262144);

    hipMemsetAsync(ws, 0, 1024, stream);
    k_keys<<<dim3(T_TOK / 256), dim3(256), 0, stream>>>(sel_idx, keys, hist);
    k_wt<<<dim3(DMD / 256, NH), dim3(256), 0, stream>>>(W, Wt);
    k_scan<<<dim3(1), dim3(64), 0, stream>>>(hist, offs, tiles, ntiles);
    k_scatter<<<dim3(T_TOK / 256), dim3(256), 0, stream>>>(keys, offs, cursor, perm);
    k_gemm<<<dim3(DMD / 128, 192), dim3(256), 0, stream>>>(
        emb, sel_prob, Wt, bias, perm, tiles, ntiles, out);
}

// Round 2
// 147.631 us; speedup vs baseline: 1.2270x; 1.2270x over previous
//
#include <hip/hip_runtime.h>
#include <hip/hip_bf16.h>

// Problem constants (B=4, S=4096, A=2, H=8, DH=128, DM=2048)
#define T_TOK 16384
#define NH 8
#define DHD 128
#define DMD 2048
#define NBUCKET 64
#define KTOT 256   // A=2 slots * DH=128

typedef __attribute__((ext_vector_type(8))) short bf16x8;
typedef __attribute__((ext_vector_type(4))) float f32x4;

__device__ inline short f2b(float x) {
    __hip_bfloat16 h = __float2bfloat16(x);
    return *reinterpret_cast<short*>(&h);
}

// async global -> LDS, 16B per lane. LDS dest must be wave-uniform base
// (HW adds lane*16); global src is per-lane.
__device__ inline void gll16(const void* g, void* l) {
    __builtin_amdgcn_global_load_lds(
        (const __attribute__((address_space(1))) void*)g,
        (__attribute__((address_space(3))) void*)l, 16, 0, 0);
}

// ---------------- ws layout (bytes) ----------------
// 0       : hist[64]     (zeroed each call)
// 256     : offsets[64]
// 512     : cursor[64]   (zeroed each call)
// 768     : ntiles
// 1024    : tiles[256][4] int (4 KB)
// 8192    : keys[16384]  (64 KB)
// 73728   : perm[16384]  (64 KB)
// 262144  : Wt  bf16 [8][2048][128]        (4 MB)
// 4456448 : Apk bf16 [16384+128][256]      (8.45 MB)

__global__ void k_keys(const int* __restrict__ idx, int* __restrict__ keys,
                       int* __restrict__ hist) {
    int t = blockIdx.x * 256 + threadIdx.x;
    if (t < T_TOK) {
        int key = idx[2 * t] * NH + idx[2 * t + 1];
        keys[t] = key;
        atomicAdd(&hist[key], 1);
    }
}

__global__ void k_scan(const int* __restrict__ hist, int* __restrict__ offs,
                       int* __restrict__ tiles, int* __restrict__ ntiles) {
    if (threadIdx.x == 0) {
        int acc = 0, nt = 0;
        for (int k = 0; k < NBUCKET; ++k) {
            offs[k] = acc;
            int n = hist[k];
            for (int s = 0; s < n; s += 128) {
                tiles[4 * nt + 0] = k;
                tiles[4 * nt + 1] = acc + s;
                tiles[4 * nt + 2] = (n - s) < 128 ? (n - s) : 128;
                tiles[4 * nt + 3] = 0;
                ++nt;
            }
            acc += n;
        }
        *ntiles = nt;
    }
}

__global__ void k_scatter(const int* __restrict__ keys, const int* __restrict__ offs,
                          int* __restrict__ cursor, int* __restrict__ perm) {
    int t = blockIdx.x * 256 + threadIdx.x;
    if (t < T_TOK) {
        int key = keys[t];
        int pos = offs[key] + atomicAdd(&cursor[key], 1);
        perm[pos] = t;
    }
}

// W [h][d][m] f32 -> Wt [h][m][d] bf16, via LDS transpose (coalesced both sides)
__global__ __launch_bounds__(256) void k_wt(const float* __restrict__ W,
                                            short* __restrict__ Wt) {
    __shared__ float Ws[DHD][65];
    int h = blockIdx.y, m0 = blockIdx.x * 64;
    int tid = threadIdx.x;
    for (int i = tid; i < DHD * 64; i += 256) {
        int d = i >> 6, m = i & 63;
        Ws[d][m] = W[((size_t)h * DHD + d) * DMD + m0 + m];
    }
    __syncthreads();
    for (int i = tid; i < 64 * 16; i += 256) {
        int m = i >> 4, d0 = (i & 15) * 8;
        bf16x8 o;
#pragma unroll
        for (int j = 0; j < 8; ++j) o[j] = f2b(Ws[d0 + j][m]);
        *(bf16x8*)(Wt + ((size_t)h * DMD + m0 + m) * DHD + d0) = o;
    }
}

// Build routed, prob-scaled A matrix: Apk[pos][k] (bf16),
// k<128 -> p0*emb[t,0,k]; k>=128 -> p1*emb[t,1,k-128]; t = perm[pos].
__global__ void k_pack(const float* __restrict__ emb, const float* __restrict__ probs,
                       const int* __restrict__ perm, short* __restrict__ Apk) {
    int gid = blockIdx.x * 256 + threadIdx.x;  // one 16B chunk each
    int pos = gid >> 5;
    int k0  = (gid & 31) * 8;
    short* dst = Apk + (size_t)pos * KTOT + k0;
    if (pos >= T_TOK) {  // zero the slack rows (tiles may read past last row)
        bf16x8 z;
#pragma unroll
        for (int j = 0; j < 8; ++j) z[j] = 0;
        *(bf16x8*)dst = z;
        return;
    }
    int t = perm[pos];
    int a = k0 >> 7;
    float p = probs[2 * t + a];
    const float* src = emb + ((size_t)(2 * t + a)) * DHD + (k0 & 127);
    f32x4 f0 = ((const f32x4*)src)[0];
    f32x4 f1 = ((const f32x4*)src)[1];
    bf16x8 o;
    o[0] = f2b(p * f0.x); o[1] = f2b(p * f0.y);
    o[2] = f2b(p * f0.z); o[3] = f2b(p * f0.w);
    o[4] = f2b(p * f1.x); o[5] = f2b(p * f1.y);
    o[6] = f2b(p * f1.z); o[7] = f2b(p * f1.w);
    *(bf16x8*)dst = o;
}

// m97-style GEMM: BM=128, BN=128, BK=64, K=256 (4 steps).
// A/B staged with global_load_lds(16B), linear LDS dest, inverse-swizzled
// source, XOR-swizzled ds_read_b128 (rule #21 / T2).
__global__ __launch_bounds__(256) void k_gemm(
    const short* __restrict__ Apk, const float* __restrict__ probs,
    const short* __restrict__ Wt, const float* __restrict__ bias,
    const int* __restrict__ perm, const int* __restrict__ tiles,
    const int* __restrict__ ntiles, float* __restrict__ out) {
    int tile_id = blockIdx.y;
    if (tile_id >= *ntiles) return;
    int key   = tiles[4 * tile_id + 0];
    int row0  = tiles[4 * tile_id + 1];
    int nrows = tiles[4 * tile_id + 2];
    int h0 = key >> 3, h1 = key & 7;
    int ncol = blockIdx.x * 128;

    __shared__ short As[128 * 64];  // [row][chunk^(row&7)] chunks of 8 bf16
    __shared__ short Bs[128 * 64];
    __shared__ int   s_tok[128];
    __shared__ float s_p0[128], s_p1[128];

    int tid = threadIdx.x;
    int lane = tid & 63, wave = tid >> 6;

    if (tid < 128) {
        int t = -1; float p0 = 0.f, p1 = 0.f;
        if (tid < nrows) {
            t = perm[row0 + tid];
            p0 = probs[2 * t];
            p1 = probs[2 * t + 1];
        }
        s_tok[tid] = t; s_p0[tid] = p0; s_p1[tid] = p1;
    }

    f32x4 acc[4][4];
#pragma unroll
    for (int i = 0; i < 4; ++i)
#pragma unroll
        for (int j = 0; j < 4; ++j) acc[i][j] = (f32x4){0.f, 0.f, 0.f, 0.f};

    int wm = (wave >> 1) * 64, wn = (wave & 1) * 64;
    int l15 = lane & 15, lq = lane >> 4;

    int srcr = tid >> 3;        // dest row within 32-row round
    int swz  = srcr & 7;        // row&7 for swizzle
    int cs   = (tid & 7) ^ swz; // inverse-swizzled source chunk

    for (int ks = 0; ks < 4; ++ks) {
        int h     = (ks < 2) ? h0 : h1;
        int kg0   = ks * 64;            // K offset within Apk row
        int dbase = (ks & 1) * 64;      // d offset within Wt row
#pragma unroll
        for (int rd = 0; rd < 4; ++rd) {
            int r = rd * 32 + srcr;
            short* ldst_a = As + (rd * 256 + wave * 64) * 8;  // wave-uniform
            short* ldst_b = Bs + (rd * 256 + wave * 64) * 8;
            gll16(Apk + (size_t)(row0 + r) * KTOT + kg0 + cs * 8, ldst_a);
            gll16(Wt + ((size_t)h * DMD + ncol + r) * DHD + dbase + cs * 8, ldst_b);
        }
        __syncthreads();

#pragma unroll
        for (int ki = 0; ki < 2; ++ki) {
            bf16x8 af[4], bfr[4];
#pragma unroll
            for (int mi = 0; mi < 4; ++mi) {
                int R  = wm + mi * 16 + l15;
                int ch = (ki * 4 + lq) ^ (R & 7);
                af[mi] = *(const bf16x8*)&As[R * 64 + ch * 8];
            }
#pragma unroll
            for (int ni = 0; ni < 4; ++ni) {
                int N  = wn + ni * 16 + l15;
                int ch = (ki * 4 + lq) ^ (N & 7);
                bfr[ni] = *(const bf16x8*)&Bs[N * 64 + ch * 8];
            }
#pragma unroll
            for (int mi = 0; mi < 4; ++mi)
#pragma unroll
                for (int ni = 0; ni < 4; ++ni)
                    acc[mi][ni] = __builtin_amdgcn_mfma_f32_16x16x32_bf16(
                        af[mi], bfr[ni], acc[mi][ni], 0, 0, 0);
        }
        __syncthreads();
    }

    // epilogue: prob-weighted bias, scatter rows to out
#pragma unroll
    for (int ni = 0; ni < 4; ++ni) {
        int c = ncol + wn + ni * 16 + l15;
        float b0 = bias[h0 * DMD + c];
        float b1 = bias[h1 * DMD + c];
#pragma unroll
        for (int mi = 0; mi < 4; ++mi) {
#pragma unroll
            for (int r = 0; r < 4; ++r) {
                int i = wm + mi * 16 + lq * 4 + r;
                int t = s_tok[i];
                if (t >= 0) {
                    out[(size_t)t * DMD + c] =
                        acc[mi][ni][r] + s_p0[i] * b0 + s_p1[i] * b1;
                }
            }
        }
    }
}

extern "C" void kernel_launch(void* const* d_in, const int* in_sizes, int n_in,
                              void* d_out, int out_size, void* d_ws, size_t ws_size,
                              hipStream_t stream) {
    const float* emb      = (const float*)d_in[0];  // (B,S,A,DH) f32
    const int*   sel_idx  = (const int*)d_in[1];    // (B,S,A) i32
    const float* sel_prob = (const float*)d_in[2];  // (B,S,A) f32
    const float* W        = (const float*)d_in[3];  // (H,DH,DM) f32
    const float* bias     = (const float*)d_in[4];  // (H,DM) f32
    float* out = (float*)d_out;

    char* ws = (char*)d_ws;
    int* hist   = (int*)(ws + 0);
    int* offs   = (int*)(ws + 256);
    int* cursor = (int*)(ws + 512);
    int* ntiles = (int*)(ws + 768);
    int* tiles  = (int*)(ws + 1024);
    int* keys   = (int*)(ws + 8192);
    int* perm   = (int*)(ws + 8192 + 65536);
    short* Wt   = (short*)(ws + 262144);
    short* Apk  = (short*)(ws + 4456448);

    hipMemsetAsync(ws, 0, 1024, stream);
    k_keys<<<dim3(T_TOK / 256), dim3(256), 0, stream>>>(sel_idx, keys, hist);
    k_wt<<<dim3(DMD / 64, NH), dim3(256), 0, stream>>>(W, Wt);
    k_scan<<<dim3(1), dim3(64), 0, stream>>>(hist, offs, tiles, ntiles);
    k_scatter<<<dim3(T_TOK / 256), dim3(256), 0, stream>>>(keys, offs, cursor, perm);
    k_pack<<<dim3((T_TOK + 128) * 32 / 256), dim3(256), 0, stream>>>(
        emb, sel_prob, perm, Apk);
    k_gemm<<<dim3(DMD / 128, 192), dim3(256), 0, stream>>>(
        Apk, sel_prob, Wt, bias, perm, tiles, ntiles, out);
}

// Round 3
// 147.199 us; speedup vs baseline: 1.2306x; 1.0029x over previous
//
#include <hip/hip_runtime.h>
#include <hip/hip_bf16.h>

// Problem constants (B=4, S=4096, A=2, H=8, DH=128, DM=2048)
#define T_TOK 16384
#define NH 8
#define DHD 128
#define DMD 2048
#define NBUCKET 64
#define KTOT 256   // A=2 slots * DH=128

typedef __attribute__((ext_vector_type(8))) short bf16x8;
typedef __attribute__((ext_vector_type(4))) float f32x4;

__device__ inline short f2b(float x) {
    __hip_bfloat16 h = __float2bfloat16(x);
    return *reinterpret_cast<short*>(&h);
}

// async global -> LDS, 16B per lane. LDS dest must be wave-uniform base
// (HW adds lane*16); global src is per-lane.
__device__ inline void gll16(const void* g, void* l) {
    __builtin_amdgcn_global_load_lds(
        (const __attribute__((address_space(1))) void*)g,
        (__attribute__((address_space(3))) void*)l, 16, 0, 0);
}

// ---------------- ws layout (bytes) ----------------
// 0       : hist[64]     (zeroed each call by k_init)
// 256     : offsets[64]
// 512     : cursor[64]   (zeroed each call by k_init)
// 768     : ntiles
// 1024    : tiles[256][4] int (4 KB)
// 8192    : keys[16384]  (64 KB)
// 73728   : perm[16384]  (64 KB)
// 262144  : Wt  bf16 [8][2048][128]        (4 MB)
// 4456448 : Apk bf16 [16384+128][256]      (8.45 MB)

// zero the 1024-byte control region (hist/offs/cursor/ntiles).
// Replaces hipMemsetAsync: the runtime's fillBufferAligned graph node was
// measured at ~80 us/replay (!) vs ~1-2 us for this kernel.
__global__ void k_init(int* __restrict__ ctrl) {
    ctrl[threadIdx.x] = 0;   // 256 threads x 4B = 1024 B
}

__global__ void k_keys(const int* __restrict__ idx, int* __restrict__ keys,
                       int* __restrict__ hist) {
    int t = blockIdx.x * 256 + threadIdx.x;
    if (t < T_TOK) {
        int key = idx[2 * t] * NH + idx[2 * t + 1];
        keys[t] = key;
        atomicAdd(&hist[key], 1);
    }
}

__global__ void k_scan(const int* __restrict__ hist, int* __restrict__ offs,
                       int* __restrict__ tiles, int* __restrict__ ntiles) {
    if (threadIdx.x == 0) {
        int acc = 0, nt = 0;
        for (int k = 0; k < NBUCKET; ++k) {
            offs[k] = acc;
            int n = hist[k];
            for (int s = 0; s < n; s += 128) {
                tiles[4 * nt + 0] = k;
                tiles[4 * nt + 1] = acc + s;
                tiles[4 * nt + 2] = (n - s) < 128 ? (n - s) : 128;
                tiles[4 * nt + 3] = 0;
                ++nt;
            }
            acc += n;
        }
        *ntiles = nt;
    }
}

__global__ void k_scatter(const int* __restrict__ keys, const int* __restrict__ offs,
                          int* __restrict__ cursor, int* __restrict__ perm) {
    int t = blockIdx.x * 256 + threadIdx.x;
    if (t < T_TOK) {
        int key = keys[t];
        int pos = offs[key] + atomicAdd(&cursor[key], 1);
        perm[pos] = t;
    }
}

// W [h][d][m] f32 -> Wt [h][m][d] bf16, via LDS transpose (coalesced both sides)
__global__ __launch_bounds__(256) void k_wt(const float* __restrict__ W,
                                            short* __restrict__ Wt) {
    __shared__ float Ws[DHD][65];
    int h = blockIdx.y, m0 = blockIdx.x * 64;
    int tid = threadIdx.x;
    for (int i = tid; i < DHD * 64; i += 256) {
        int d = i >> 6, m = i & 63;
        Ws[d][m] = W[((size_t)h * DHD + d) * DMD + m0 + m];
    }
    __syncthreads();
    for (int i = tid; i < 64 * 16; i += 256) {
        int m = i >> 4, d0 = (i & 15) * 8;
        bf16x8 o;
#pragma unroll
        for (int j = 0; j < 8; ++j) o[j] = f2b(Ws[d0 + j][m]);
        *(bf16x8*)(Wt + ((size_t)h * DMD + m0 + m) * DHD + d0) = o;
    }
}

// Build routed, prob-scaled A matrix: Apk[pos][k] (bf16),
// k<128 -> p0*emb[t,0,k]; k>=128 -> p1*emb[t,1,k-128]; t = perm[pos].
__global__ void k_pack(const float* __restrict__ emb, const float* __restrict__ probs,
                       const int* __restrict__ perm, short* __restrict__ Apk) {
    int gid = blockIdx.x * 256 + threadIdx.x;  // one 16B chunk each
    int pos = gid >> 5;
    int k0  = (gid & 31) * 8;
    short* dst = Apk + (size_t)pos * KTOT + k0;
    if (pos >= T_TOK) {  // zero the slack rows (tiles may read past last row)
        bf16x8 z;
#pragma unroll
        for (int j = 0; j < 8; ++j) z[j] = 0;
        *(bf16x8*)dst = z;
        return;
    }
    int t = perm[pos];
    int a = k0 >> 7;
    float p = probs[2 * t + a];
    const float* src = emb + ((size_t)(2 * t + a)) * DHD + (k0 & 127);
    f32x4 f0 = ((const f32x4*)src)[0];
    f32x4 f1 = ((const f32x4*)src)[1];
    bf16x8 o;
    o[0] = f2b(p * f0.x); o[1] = f2b(p * f0.y);
    o[2] = f2b(p * f0.z); o[3] = f2b(p * f0.w);
    o[4] = f2b(p * f1.x); o[5] = f2b(p * f1.y);
    o[6] = f2b(p * f1.z); o[7] = f2b(p * f1.w);
    *(bf16x8*)dst = o;
}

// m97-style GEMM: BM=128, BN=128, BK=64, K=256 (4 steps).
// A/B staged with global_load_lds(16B), linear LDS dest, inverse-swizzled
// source, XOR-swizzled ds_read_b128 (rule #21 / T2).
__global__ __launch_bounds__(256) void k_gemm(
    const short* __restrict__ Apk, const float* __restrict__ probs,
    const short* __restrict__ Wt, const float* __restrict__ bias,
    const int* __restrict__ perm, const int* __restrict__ tiles,
    const int* __restrict__ ntiles, float* __restrict__ out) {
    int tile_id = blockIdx.y;
    if (tile_id >= *ntiles) return;
    int key   = tiles[4 * tile_id + 0];
    int row0  = tiles[4 * tile_id + 1];
    int nrows = tiles[4 * tile_id + 2];
    int h0 = key >> 3, h1 = key & 7;
    int ncol = blockIdx.x * 128;

    __shared__ short As[128 * 64];  // [row][chunk^(row&7)] chunks of 8 bf16
    __shared__ short Bs[128 * 64];
    __shared__ int   s_tok[128];
    __shared__ float s_p0[128], s_p1[128];

    int tid = threadIdx.x;
    int lane = tid & 63, wave = tid >> 6;

    if (tid < 128) {
        int t = -1; float p0 = 0.f, p1 = 0.f;
        if (tid < nrows) {
            t = perm[row0 + tid];
            p0 = probs[2 * t];
            p1 = probs[2 * t + 1];
        }
        s_tok[tid] = t; s_p0[tid] = p0; s_p1[tid] = p1;
    }

    f32x4 acc[4][4];
#pragma unroll
    for (int i = 0; i < 4; ++i)
#pragma unroll
        for (int j = 0; j < 4; ++j) acc[i][j] = (f32x4){0.f, 0.f, 0.f, 0.f};

    int wm = (wave >> 1) * 64, wn = (wave & 1) * 64;
    int l15 = lane & 15, lq = lane >> 4;

    int srcr = tid >> 3;        // dest row within 32-row round
    int swz  = srcr & 7;        // row&7 for swizzle
    int cs   = (tid & 7) ^ swz; // inverse-swizzled source chunk

    for (int ks = 0; ks < 4; ++ks) {
        int h     = (ks < 2) ? h0 : h1;
        int kg0   = ks * 64;            // K offset within Apk row
        int dbase = (ks & 1) * 64;      // d offset within Wt row
#pragma unroll
        for (int rd = 0; rd < 4; ++rd) {
            int r = rd * 32 + srcr;
            short* ldst_a = As + (rd * 256 + wave * 64) * 8;  // wave-uniform
            short* ldst_b = Bs + (rd * 256 + wave * 64) * 8;
            gll16(Apk + (size_t)(row0 + r) * KTOT + kg0 + cs * 8, ldst_a);
            gll16(Wt + ((size_t)h * DMD + ncol + r) * DHD + dbase + cs * 8, ldst_b);
        }
        __syncthreads();

#pragma unroll
        for (int ki = 0; ki < 2; ++ki) {
            bf16x8 af[4], bfr[4];
#pragma unroll
            for (int mi = 0; mi < 4; ++mi) {
                int R  = wm + mi * 16 + l15;
                int ch = (ki * 4 + lq) ^ (R & 7);
                af[mi] = *(const bf16x8*)&As[R * 64 + ch * 8];
            }
#pragma unroll
            for (int ni = 0; ni < 4; ++ni) {
                int N  = wn + ni * 16 + l15;
                int ch = (ki * 4 + lq) ^ (N & 7);
                bfr[ni] = *(const bf16x8*)&Bs[N * 64 + ch * 8];
            }
#pragma unroll
            for (int mi = 0; mi < 4; ++mi)
#pragma unroll
                for (int ni = 0; ni < 4; ++ni)
                    acc[mi][ni] = __builtin_amdgcn_mfma_f32_16x16x32_bf16(
                        af[mi], bfr[ni], acc[mi][ni], 0, 0, 0);
        }
        __syncthreads();
    }

    // epilogue: prob-weighted bias, scatter rows to out
#pragma unroll
    for (int ni = 0; ni < 4; ++ni) {
        int c = ncol + wn + ni * 16 + l15;
        float b0 = bias[h0 * DMD + c];
        float b1 = bias[h1 * DMD + c];
#pragma unroll
        for (int mi = 0; mi < 4; ++mi) {
#pragma unroll
            for (int r = 0; r < 4; ++r) {
                int i = wm + mi * 16 + lq * 4 + r;
                int t = s_tok[i];
                if (t >= 0) {
                    out[(size_t)t * DMD + c] =
                        acc[mi][ni][r] + s_p0[i] * b0 + s_p1[i] * b1;
                }
            }
        }
    }
}

extern "C" void kernel_launch(void* const* d_in, const int* in_sizes, int n_in,
                              void* d_out, int out_size, void* d_ws, size_t ws_size,
                              hipStream_t stream) {
    const float* emb      = (const float*)d_in[0];  // (B,S,A,DH) f32
    const int*   sel_idx  = (const int*)d_in[1];    // (B,S,A) i32
    const float* sel_prob = (const float*)d_in[2];  // (B,S,A) f32
    const float* W        = (const float*)d_in[3];  // (H,DH,DM) f32
    const float* bias     = (const float*)d_in[4];  // (H,DM) f32
    float* out = (float*)d_out;

    char* ws = (char*)d_ws;
    int* ctrl   = (int*)(ws + 0);
    int* hist   = (int*)(ws + 0);
    int* offs   = (int*)(ws + 256);
    int* cursor = (int*)(ws + 512);
    int* ntiles = (int*)(ws + 768);
    int* tiles  = (int*)(ws + 1024);
    int* keys   = (int*)(ws + 8192);
    int* perm   = (int*)(ws + 8192 + 65536);
    short* Wt   = (short*)(ws + 262144);
    short* Apk  = (short*)(ws + 4456448);

    k_init<<<dim3(1), dim3(256), 0, stream>>>(ctrl);
    k_keys<<<dim3(T_TOK / 256), dim3(256), 0, stream>>>(sel_idx, keys, hist);
    k_wt<<<dim3(DMD / 64, NH), dim3(256), 0, stream>>>(W, Wt);
    k_scan<<<dim3(1), dim3(64), 0, stream>>>(hist, offs, tiles, ntiles);
    k_scatter<<<dim3(T_TOK / 256), dim3(256), 0, stream>>>(keys, offs, cursor, perm);
    k_pack<<<dim3((T_TOK + 128) * 32 / 256), dim3(256), 0, stream>>>(
        emb, sel_prob, perm, Apk);
    k_gemm<<<dim3(DMD / 128, 192), dim3(256), 0, stream>>>(
        Apk, sel_prob, Wt, bias, perm, tiles, ntiles, out);
}